// Round 20
// baseline (264.275 us; speedup 1.0000x reference)
//
#include <hip/hip_runtime.h>
#include <hip/hip_cooperative_groups.h>

namespace cg = cooperative_groups;

#define HH 16
#define LL 2048
#define DD 64
#define BQ 128
#define BK 64
#define NQ (LL/BQ)   /* 16 */
#define NK (LL/BK)   /* 32 */
#define SCALE 0.125f
#define QSCALE (0.125f * 1.44269504f)   /* fold log2(e): softmax via exp2 */

typedef __attribute__((ext_vector_type(8))) short s8v;   // 8 bf16 (4 VGPR)
typedef __attribute__((ext_vector_type(4))) float f4v;   // 4 fp32 acc

static __device__ __forceinline__ ushort f2bf(float x) {
    unsigned u = __float_as_uint(x);
    u += 0x7fff + ((u >> 16) & 1);       // round-to-nearest-even
    return (ushort)(u >> 16);
}

// ---------------- kernel 1: per-head k partial sums ----------------
__global__ void kmean1_kernel(const float* __restrict__ k, float* __restrict__ kpart) {
    int b = blockIdx.x;             // 0..7 token slab of 256
    int h = blockIdx.y;
    int t = threadIdx.x;            // 256
    int d = t & 63, c = t >> 6;
    const float* kh = k + ((size_t)h*LL + (size_t)b*256) * DD;
    float s = 0.f;
    for (int l = c*64; l < c*64 + 64; ++l) s += kh[(size_t)l * DD + d];
    __shared__ float red[4][64];
    red[c][d] = s;
    __syncthreads();
    if (t < 64) kpart[((size_t)h*8 + b)*64 + t] = red[0][t]+red[1][t]+red[2][t]+red[3][t];
}

// ---------------- kernel 2: fused stats + bf16 converts + bmask (cooperative) ----------------
// Phase 1: per-block stats/converts (as proven). grid.sync(). Phase 2: blocks
// 0..255 compute the (h,qi) block-selection mask — r15 bmask math verbatim.
__global__ __launch_bounds__(128, 2) void stats_kernel(
        const float* __restrict__ q, const float* __restrict__ k, const float* __restrict__ v,
        const float* __restrict__ kpart, const float* __restrict__ simth,
        float* __restrict__ qm, float* __restrict__ km,
        int* __restrict__ compq, int* __restrict__ compk,
        ushort* __restrict__ qb, ushort* __restrict__ kb, ushort* __restrict__ vTb,
        const float* __restrict__ cdfth, unsigned* __restrict__ bmaskbits) {
    __shared__ __align__(16) char smem[34304];
    int h = blockIdx.y, t = threadIdx.x;

    if ((int)blockIdx.x < NQ) {
        // ---------- q path ----------
        int qi = blockIdx.x;
        float (*xs)[DD+1] = (float(*)[DD+1])smem;         // 128*65*4 = 33280
        float* mean = (float*)(smem + 33280);             // 256
        float* red  = (float*)(smem + 33536);             // 512
        size_t row = (size_t)h*LL + (size_t)qi*BQ + t;
        const float* rp = q + row * DD;
        float x[DD]; float n2 = 0.f;
        #pragma unroll
        for (int d = 0; d < DD; d += 4) {
            float4 v4 = *(const float4*)(rp + d);
            x[d]=v4.x; x[d+1]=v4.y; x[d+2]=v4.z; x[d+3]=v4.w;
            n2 += v4.x*v4.x + v4.y*v4.y + v4.z*v4.z + v4.w*v4.w;
        }
        #pragma unroll
        for (int d = 0; d < DD; d += 4) {
            ushort4 o;
            o.x = f2bf(x[d]*QSCALE);   o.y = f2bf(x[d+1]*QSCALE);
            o.z = f2bf(x[d+2]*QSCALE); o.w = f2bf(x[d+3]*QSCALE);
            *(ushort4*)(qb + row*DD + d) = o;
        }
        #pragma unroll
        for (int d = 0; d < DD; ++d) xs[t][d] = x[d];
        __syncthreads();
        {   // parallel partial column sums: thread t = (half, d)
            int d = t & 63, hf = t >> 6;
            float s = 0.f;
            for (int r = hf*64; r < hf*64 + 64; ++r) s += xs[r][d];
            red[t] = s;
        }
        __syncthreads();
        if (t < DD) mean[t] = (red[t] + red[64 + t]) * (1.0f/BQ);
        __syncthreads();
        float dot = 0.f, m2 = 0.f;
        #pragma unroll
        for (int d = 0; d < DD; ++d) { dot += x[d]*mean[d]; m2 += mean[d]*mean[d]; }
        float cs = dot / ((sqrtf(n2) + 1e-6f) * (sqrtf(m2) + 1e-6f));
        __syncthreads();
        red[t] = cs; __syncthreads();
        for (int sft = BQ/2; sft > 0; sft >>= 1) {
            if (t < sft) red[t] += red[t + sft];
            __syncthreads();
        }
        if (t == 0) compq[h*NQ + qi] = (red[0] * (1.0f/BQ)) > simth[h] ? 1 : 0;
        if (t < DD) qm[((size_t)h*NQ + qi)*DD + t] = mean[t];
    } else {
        // ---------- k/v path ----------
        int ki = blockIdx.x - NQ;
        float* mu_s = (float*)smem;                               // 256
        float (*xs)[DD+1] = (float(*)[DD+1])(smem + 256);         // 64*65*4 = 16640
        ushort (*vs)[66]  = (ushort(*)[66])(smem + 256 + 16640);  // 8448
        float* mean = (float*)(smem + 256 + 16640 + 8448);        // 256
        float* red  = (float*)(smem + 256 + 16640 + 8448 + 256);  // 256
        if (t < 64) {
            float s = 0.f;
            #pragma unroll
            for (int b = 0; b < 8; ++b) s += kpart[((size_t)h*8 + b)*64 + t];
            mu_s[t] = s * (1.0f/LL);
        }
        __syncthreads();
        size_t rowb = (size_t)h*LL + (size_t)ki*BK;
        float x[DD]; float n2 = 0.f;
        if (t < 64) {
            const float* rp = k + (rowb + t) * DD;
            #pragma unroll
            for (int d = 0; d < DD; d += 4) {
                float4 v4 = *(const float4*)(rp + d);
                v4.x -= mu_s[d]; v4.y -= mu_s[d+1]; v4.z -= mu_s[d+2]; v4.w -= mu_s[d+3];
                x[d]=v4.x; x[d+1]=v4.y; x[d+2]=v4.z; x[d+3]=v4.w;
                n2 += v4.x*v4.x + v4.y*v4.y + v4.z*v4.z + v4.w*v4.w;
            }
            #pragma unroll
            for (int d = 0; d < DD; d += 4) {
                ushort4 o;
                o.x = f2bf(x[d]);   o.y = f2bf(x[d+1]);
                o.z = f2bf(x[d+2]); o.w = f2bf(x[d+3]);
                *(ushort4*)(kb + (rowb + t)*DD + d) = o;
            }
            #pragma unroll
            for (int d = 0; d < DD; ++d) xs[t][d] = x[d];
        } else {
            int tk = t - 64;
            const float* vp = v + (rowb + tk) * DD;
            #pragma unroll
            for (int d = 0; d < DD; d += 4) {
                float4 v4 = *(const float4*)(vp + d);
                vs[tk][d]   = f2bf(v4.x); vs[tk][d+1] = f2bf(v4.y);
                vs[tk][d+2] = f2bf(v4.z); vs[tk][d+3] = f2bf(v4.w);
            }
        }
        __syncthreads();
        if (t < 64) {
            size_t vbase = ((size_t)h*DD + t)*LL + (size_t)ki*64;
            #pragma unroll
            for (int r8 = 0; r8 < 64; r8 += 8) {
                s8v o;
                #pragma unroll
                for (int e = 0; e < 8; ++e) o[e] = (short)vs[r8+e][t];
                *(s8v*)(vTb + vbase + r8) = o;
            }
            float s = 0.f;
            for (int r = 0; r < BK; ++r) s += xs[r][t];
            mean[t] = s * (1.0f/BK);
        }
        __syncthreads();
        if (t < 64) {
            float dot = 0.f, m2 = 0.f;
            #pragma unroll
            for (int d = 0; d < DD; ++d) { dot += x[d]*mean[d]; m2 += mean[d]*mean[d]; }
            float cs = dot / ((sqrtf(n2) + 1e-6f) * (sqrtf(m2) + 1e-6f));
            red[t] = cs;
        }
        __syncthreads();
        for (int sft = 32; sft > 0; sft >>= 1) {
            if (t < sft) red[t] += red[t + sft];
            __syncthreads();
        }
        if (t == 0) compk[h*NK + ki] = (red[0] * (1.0f/BK)) > simth[h] ? 1 : 0;
        if (t < 64) km[((size_t)h*NK + ki)*DD + t] = mean[t];
    }

    // ---- grid-wide sync, then phase 2: bmask (r15 math verbatim) ----
    __threadfence();
    cg::this_grid().sync();
    __threadfence();

    int b = blockIdx.y * gridDim.x + blockIdx.x;
    if (b < NQ*HH) {
        int h2 = b >> 4, qi2 = b & 15;
        float* ssh = (float*)smem;        // 32
        float* pp  = ssh + 32;            // 32
        if (t < NK) {
            const float* qv = qm + ((size_t)h2*NQ + qi2)*DD;
            const float* kv = km + ((size_t)h2*NK + t)*DD;
            float s = 0.f;
            for (int d = 0; d < DD; ++d) s += qv[d]*kv[d];
            ssh[t] = s * SCALE;
        }
        __syncthreads();
        if (t < NK) {
            float m = ssh[0];
            for (int i = 1; i < NK; ++i) m = fmaxf(m, ssh[i]);
            float den = 0.f;
            for (int i = 0; i < NK; ++i) den += expf(ssh[i] - m);
            pp[t] = expf(ssh[t] - m) / den;
        }
        __syncthreads();
        if (t < NK) {
            float pj = pp[t];
            float mass = 0.f;
            for (int i = 0; i < NK; ++i) {
                float pi = pp[i];
                if (pi > pj || (pi == pj && i < t)) mass += pi;
            }
            int sel = (mass < cdfth[h2]) ? 1 : 0;
            int keep = (sel || !(compq[h2*NQ+qi2] && compk[h2*NK+t])) ? 1 : 0;
            unsigned long long bal = __ballot(keep);   // lanes >=32 inactive -> 0
            if (t == 0) bmaskbits[h2*NQ + qi2] = (unsigned)bal;
        }
    }
}

// ---------------- kernel 3: wave-autonomous masked flash attention (64q/wave) ----------------
// r15's proven kernel VERBATIM (attn 43 us): external bitmask, block =
// (h, qi, half) via XCD-aware 1D grid, 4 waves rank-splitting the selected
// k-blocks, 64q x 64k per iter, direct-from-L2 fragments, V after QK^T.
__global__ __launch_bounds__(256, 2) void attn_kernel(
        const ushort* __restrict__ qb, const ushort* __restrict__ kb,
        const ushort* __restrict__ vTb, const unsigned* __restrict__ bmaskbits,
        float* __restrict__ out) {
    // LDS: [0,36864) per-wave P tiles [64][72] ushort (main loop),
    //      UNION [0,67584) O-merge [4][64][66] f32 (epilogue),
    //      [67584,68608) m[4][64], [68608,69632) l[4][64]
    __shared__ __align__(16) char shmem[69632];
    ushort* pl = (ushort*)shmem + (threadIdx.x >> 6) * 64 * 72;
    float*  Ob = (float*)shmem;                     // stride 4224 floats per wave
    float*  mb = (float*)(shmem + 67584);
    float*  lb = (float*)(shmem + 68608);

    int bid  = blockIdx.x;
    int slot = bid >> 3;
    int h    = ((slot >> 5) << 3) | (bid & 7);
    int qi   = (slot & 31) >> 1;
    int half = slot & 1;
    int tid  = threadIdx.x;
    int w    = tid >> 6;
    int l    = tid & 63;
    int lo = l & 15, hi = l >> 4;
    int r0 = qi*BQ + half*64;                // base of this block's 64 q-rows

    unsigned msk = bmaskbits[h*NQ + qi];

    const ushort* qh = qb  + (size_t)h*LL*DD;
    const ushort* kh = kb  + (size_t)h*LL*DD;
    const ushort* vh = vTb + (size_t)h*DD*LL;

    // Q B-frags for all 4 q-tiles
    s8v qf[4][2];
    #pragma unroll
    for (int qt = 0; qt < 4; ++qt)
        #pragma unroll
        for (int kk = 0; kk < 2; ++kk)
            qf[qt][kk] = *(const s8v*)(qh + (size_t)(r0 + qt*16 + lo)*DD + kk*32 + hi*8);

    f4v O[4][4];
    float m[4], lsum[4];
    #pragma unroll
    for (int qt = 0; qt < 4; ++qt) {
        m[qt] = -1e30f; lsum[qt] = 0.f;
        #pragma unroll
        for (int dt = 0; dt < 4; ++dt) O[qt][dt] = (f4v){0.f,0.f,0.f,0.f};
    }

    unsigned mm = msk; int rank = 0;
    while (mm) {
        int j = __ffs(mm) - 1; mm &= mm - 1;
        if (((rank++) & 3) != w) continue;     // rank-split across waves

        const ushort* kbj = kh + (size_t)j*BK*DD;
        const ushort* vbj = vh + (size_t)j*BK;

        // K A-frags direct from L2
        s8v kf[4][2];
        #pragma unroll
        for (int kt = 0; kt < 4; ++kt)
            #pragma unroll
            for (int kk = 0; kk < 2; ++kk)
                kf[kt][kk] = *(const s8v*)(kbj + (size_t)(kt*16 + lo)*DD + kk*32 + hi*8);

        // S^T = K . Q^T : lane holds S[k=kt*16+hi*4+r][q=qt*16+lo]
        f4v S[4][4];
        #pragma unroll
        for (int kt = 0; kt < 4; ++kt)
            #pragma unroll
            for (int qt = 0; qt < 4; ++qt)
                S[kt][qt] = (f4v){0.f,0.f,0.f,0.f};
        __builtin_amdgcn_s_setprio(1);
        #pragma unroll
        for (int kk = 0; kk < 2; ++kk)
            #pragma unroll
            for (int kt = 0; kt < 4; ++kt)
                #pragma unroll
                for (int qt = 0; qt < 4; ++qt)
                    S[kt][qt] = __builtin_amdgcn_mfma_f32_16x16x32_bf16(kf[kt][kk], qf[qt][kk], S[kt][qt], 0, 0, 0);
        __builtin_amdgcn_s_setprio(0);

        // V B-frags after QK^T: latency hides under softmax + P pack
        s8v vf[2][4];
        #pragma unroll
        for (int kk = 0; kk < 2; ++kk)
            #pragma unroll
            for (int dt = 0; dt < 4; ++dt)
                vf[kk][dt] = *(const s8v*)(vbj + (size_t)(dt*16 + lo)*LL + kk*32 + hi*8);

        // per-q (=qt*16+lo) max over this wave's 64 k
        float pm[4];
        #pragma unroll
        for (int qt = 0; qt < 4; ++qt) {
            float a0 = fmaxf(fmaxf(S[0][qt][0],S[0][qt][1]), fmaxf(S[0][qt][2],S[0][qt][3]));
            float a1 = fmaxf(fmaxf(S[1][qt][0],S[1][qt][1]), fmaxf(S[1][qt][2],S[1][qt][3]));
            float a2 = fmaxf(fmaxf(S[2][qt][0],S[2][qt][1]), fmaxf(S[2][qt][2],S[2][qt][3]));
            float a3 = fmaxf(fmaxf(S[3][qt][0],S[3][qt][1]), fmaxf(S[3][qt][2],S[3][qt][3]));
            float p = fmaxf(fmaxf(a0,a1), fmaxf(a2,a3));
            p = fmaxf(p, __shfl_xor(p, 16));
            p = fmaxf(p, __shfl_xor(p, 32));
            pm[qt] = p;
        }
        bool grow = (pm[0] > m[0]+8.0f) | (pm[1] > m[1]+8.0f) |
                    (pm[2] > m[2]+8.0f) | (pm[3] > m[3]+8.0f);
        if (__any(grow)) {                      // defer-max (T13)
            float alpha[4];
            #pragma unroll
            for (int qt = 0; qt < 4; ++qt) {
                float mn = fmaxf(m[qt], pm[qt]);
                alpha[qt] = __builtin_amdgcn_exp2f(m[qt] - mn);
                lsum[qt] *= alpha[qt];
                m[qt] = mn;
            }
            #pragma unroll
            for (int qt = 0; qt < 4; ++qt)
                #pragma unroll
                for (int r = 0; r < 4; ++r) {
                    float a = __shfl(alpha[qt], hi*4 + r);   // alpha of q-row qt*16+hi*4+r
                    #pragma unroll
                    for (int dt = 0; dt < 4; ++dt) O[qt][dt][r] *= a;
                }
        }
        // P = exp2(S - m), pack to per-wave plds [q][k] (stride 72)
        #pragma unroll
        for (int qt = 0; qt < 4; ++qt) {
            float ps = 0.f;
            #pragma unroll
            for (int kt = 0; kt < 4; ++kt) {
                float p0 = __builtin_amdgcn_exp2f(S[kt][qt][0] - m[qt]);
                float p1 = __builtin_amdgcn_exp2f(S[kt][qt][1] - m[qt]);
                float p2 = __builtin_amdgcn_exp2f(S[kt][qt][2] - m[qt]);
                float p3 = __builtin_amdgcn_exp2f(S[kt][qt][3] - m[qt]);
                ps += (p0 + p1) + (p2 + p3);
                unsigned c01, c23;
                asm("v_cvt_pk_bf16_f32 %0, %1, %2" : "=v"(c01) : "v"(p0), "v"(p1));
                asm("v_cvt_pk_bf16_f32 %0, %1, %2" : "=v"(c23) : "v"(p2), "v"(p3));
                *(uint2*)&pl[(qt*16 + lo)*72 + kt*16 + hi*4] = make_uint2(c01, c23);
            }
            lsum[qt] += ps;
        }
        // PV: O[q][d] += P . V  (P as A-frag from plds; V from regs)
        __builtin_amdgcn_s_setprio(1);
        #pragma unroll
        for (int qt = 0; qt < 4; ++qt)
            #pragma unroll
            for (int kk = 0; kk < 2; ++kk) {
                s8v pa = *(const s8v*)&pl[(qt*16 + lo)*72 + kk*32 + hi*8];
                #pragma unroll
                for (int dt = 0; dt < 4; ++dt)
                    O[qt][dt] = __builtin_amdgcn_mfma_f32_16x16x32_bf16(pa, vf[kk][dt], O[qt][dt], 0, 0, 0);
            }
        __builtin_amdgcn_s_setprio(0);
    }

    // finish per-wave row-sums (reduce over hi groups)
    #pragma unroll
    for (int qt = 0; qt < 4; ++qt) {
        lsum[qt] += __shfl_xor(lsum[qt], 16);
        lsum[qt] += __shfl_xor(lsum[qt], 32);
    }

    __syncthreads();    // all waves done with plds (Ob overlaps it)

    if (hi == 0) {
        #pragma unroll
        for (int qt = 0; qt < 4; ++qt) {
            mb[w*64 + qt*16 + lo] = m[qt];
            lb[w*64 + qt*16 + lo] = lsum[qt];
        }
    }
    #pragma unroll
    for (int qt = 0; qt < 4; ++qt)
        #pragma unroll
        for (int dt = 0; dt < 4; ++dt)
            #pragma unroll
            for (int r = 0; r < 4; ++r)
                Ob[w*4224 + (qt*16 + hi*4 + r)*66 + dt*16 + lo] = O[qt][dt][r];
    __syncthreads();

    // merge: lane q = l handles all 64 q-rows' d-slice [w*16, w*16+16)
    {
        int q = l;
        float mw0 = mb[q], mw1 = mb[64+q], mw2 = mb[128+q], mw3 = mb[192+q];
        float ms = fmaxf(fmaxf(mw0,mw1), fmaxf(mw2,mw3));
        float c0 = __builtin_amdgcn_exp2f(mw0 - ms);
        float c1 = __builtin_amdgcn_exp2f(mw1 - ms);
        float c2 = __builtin_amdgcn_exp2f(mw2 - ms);
        float c3 = __builtin_amdgcn_exp2f(mw3 - ms);
        float ls = lb[q]*c0 + lb[64+q]*c1 + lb[128+q]*c2 + lb[192+q]*c3;
        float inv = 1.0f / ls;
        float* orow = out + ((size_t)h*LL + r0 + q)*DD + w*16;
        #pragma unroll
        for (int i4 = 0; i4 < 4; ++i4) {
            float4 o;
            #pragma unroll
            for (int e = 0; e < 4; ++e) {
                int d = w*16 + i4*4 + e;
                float acc = Ob[q*66 + d]*c0 + Ob[4224 + q*66 + d]*c1
                          + Ob[8448 + q*66 + d]*c2 + Ob[12672 + q*66 + d]*c3;
                ((float*)&o)[e] = acc * inv;
            }
            *(float4*)(orow + i4*4) = o;
        }
    }
}

extern "C" void kernel_launch(void* const* d_in, const int* in_sizes, int n_in,
                              void* d_out, int out_size, void* d_ws, size_t ws_size,
                              hipStream_t stream) {
    const float* q     = (const float*)d_in[0];
    const float* k     = (const float*)d_in[1];
    const float* v     = (const float*)d_in[2];
    const float* simth = (const float*)d_in[3];
    const float* cdfth = (const float*)d_in[4];
    float* out = (float*)d_out;

    float* ws    = (float*)d_ws;
    float* kpart = ws;                       // 16*8*64
    float* qm    = kpart + HH*8*64;          // 16*16*64
    float* km    = qm + HH*NQ*DD;            // 16*32*64
    int*   compq = (int*)(km + HH*NK*DD);    // 256
    int*   compk = compq + HH*NQ;            // 512
    unsigned* bmb = (unsigned*)(compk + HH*NK);  // 256
    size_t off = (size_t)((char*)(bmb + HH*NQ) - (char*)d_ws);
    off = (off + 15) & ~(size_t)15;
    ushort* qbuf = (ushort*)((char*)d_ws + off);
    ushort* kbuf = qbuf + (size_t)HH*LL*DD;
    ushort* vTb  = kbuf + (size_t)HH*LL*DD;

    kmean1_kernel<<<dim3(8, HH), 256, 0, stream>>>(k, kpart);

    {
        void* args[] = {
            (void*)&q, (void*)&k, (void*)&v, (void*)&kpart, (void*)&simth,
            (void*)&qm, (void*)&km, (void*)&compq, (void*)&compk,
            (void*)&qbuf, (void*)&kbuf, (void*)&vTb,
            (void*)&cdfth, (void*)&bmb
        };
        hipLaunchCooperativeKernel((const void*)stats_kernel,
                                   dim3(NQ + NK, HH), dim3(128),
                                   args, 0, stream);
    }

    attn_kernel<<<dim3(NQ*2*HH), 256, 0, stream>>>(qbuf, kbuf, vTb, bmb, out);
}

// Round 21
// 150.483 us; speedup vs baseline: 1.7562x; 1.7562x over previous
//
#include <hip/hip_runtime.h>

#define HH 16
#define LL 2048
#define DD 64
#define BQ 128
#define BK 64
#define NQ (LL/BQ)   /* 16 */
#define NK (LL/BK)   /* 32 */
#define SCALE 0.125f
#define QSCALE (0.125f * 1.44269504f)   /* fold log2(e): softmax via exp2 */

typedef __attribute__((ext_vector_type(8))) short s8v;   // 8 bf16 (4 VGPR)
typedef __attribute__((ext_vector_type(4))) float f4v;   // 4 fp32 acc

static __device__ __forceinline__ ushort f2bf(float x) {
    unsigned u = __float_as_uint(x);
    u += 0x7fff + ((u >> 16) & 1);       // round-to-nearest-even
    return (ushort)(u >> 16);
}

// ---------------- kernel 1: per-head k partial sums (+ zero bmask counters) ----------------
__global__ void kmean1_kernel(const float* __restrict__ k, float* __restrict__ kpart,
                              int* __restrict__ cnt) {
    int b = blockIdx.x;             // 0..7 token slab of 256
    int h = blockIdx.y;
    int t = threadIdx.x;            // 256
    if (b == 0 && t == 0) cnt[h] = 0;     // re-armed every call (replay-safe)
    int d = t & 63, c = t >> 6;
    const float* kh = k + ((size_t)h*LL + (size_t)b*256) * DD;
    float s = 0.f;
    for (int l = c*64; l < c*64 + 64; ++l) s += kh[(size_t)l * DD + d];
    __shared__ float red[4][64];
    red[c][d] = s;
    __syncthreads();
    if (t < 64) kpart[((size_t)h*8 + b)*64 + t] = red[0][t]+red[1][t]+red[2][t]+red[3][t];
}

// ---------------- kernel 2: fused stats + bf16 converts + last-block bmask ----------------
// Per-block stats/converts as proven. Then each block releases its writes and
// bumps cnt[h]; the 48th (last) block of head h computes the bmask for all 16
// qi of that head — r15 bmask math verbatim (bit-identical selection).
__global__ __launch_bounds__(128) void stats_kernel(
        const float* __restrict__ q, const float* __restrict__ k, const float* __restrict__ v,
        const float* __restrict__ kpart, const float* __restrict__ simth,
        float* __restrict__ qm, float* __restrict__ km,
        int* __restrict__ compq, int* __restrict__ compk,
        ushort* __restrict__ qb, ushort* __restrict__ kb, ushort* __restrict__ vTb,
        const float* __restrict__ cdfth, unsigned* __restrict__ bmaskbits,
        int* __restrict__ cnt) {
    __shared__ __align__(16) char smem[34304];
    int h = blockIdx.y, t = threadIdx.x;

    if ((int)blockIdx.x < NQ) {
        // ---------- q path ----------
        int qi = blockIdx.x;
        float (*xs)[DD+1] = (float(*)[DD+1])smem;         // 128*65*4 = 33280
        float* mean = (float*)(smem + 33280);             // 256
        float* red  = (float*)(smem + 33536);             // 512
        size_t row = (size_t)h*LL + (size_t)qi*BQ + t;
        const float* rp = q + row * DD;
        float x[DD]; float n2 = 0.f;
        #pragma unroll
        for (int d = 0; d < DD; d += 4) {
            float4 v4 = *(const float4*)(rp + d);
            x[d]=v4.x; x[d+1]=v4.y; x[d+2]=v4.z; x[d+3]=v4.w;
            n2 += v4.x*v4.x + v4.y*v4.y + v4.z*v4.z + v4.w*v4.w;
        }
        #pragma unroll
        for (int d = 0; d < DD; d += 4) {
            ushort4 o;
            o.x = f2bf(x[d]*QSCALE);   o.y = f2bf(x[d+1]*QSCALE);
            o.z = f2bf(x[d+2]*QSCALE); o.w = f2bf(x[d+3]*QSCALE);
            *(ushort4*)(qb + row*DD + d) = o;
        }
        #pragma unroll
        for (int d = 0; d < DD; ++d) xs[t][d] = x[d];
        __syncthreads();
        {   // parallel partial column sums: thread t = (half, d)
            int d = t & 63, hf = t >> 6;
            float s = 0.f;
            for (int r = hf*64; r < hf*64 + 64; ++r) s += xs[r][d];
            red[t] = s;
        }
        __syncthreads();
        if (t < DD) mean[t] = (red[t] + red[64 + t]) * (1.0f/BQ);
        __syncthreads();
        float dot = 0.f, m2 = 0.f;
        #pragma unroll
        for (int d = 0; d < DD; ++d) { dot += x[d]*mean[d]; m2 += mean[d]*mean[d]; }
        float cs = dot / ((sqrtf(n2) + 1e-6f) * (sqrtf(m2) + 1e-6f));
        __syncthreads();
        red[t] = cs; __syncthreads();
        for (int sft = BQ/2; sft > 0; sft >>= 1) {
            if (t < sft) red[t] += red[t + sft];
            __syncthreads();
        }
        if (t == 0) compq[h*NQ + qi] = (red[0] * (1.0f/BQ)) > simth[h] ? 1 : 0;
        if (t < DD) qm[((size_t)h*NQ + qi)*DD + t] = mean[t];
    } else {
        // ---------- k/v path ----------
        int ki = blockIdx.x - NQ;
        float* mu_s = (float*)smem;                               // 256
        float (*xs)[DD+1] = (float(*)[DD+1])(smem + 256);         // 64*65*4 = 16640
        ushort (*vs)[66]  = (ushort(*)[66])(smem + 256 + 16640);  // 8448
        float* mean = (float*)(smem + 256 + 16640 + 8448);        // 256
        float* red  = (float*)(smem + 256 + 16640 + 8448 + 256);  // 256
        if (t < 64) {
            float s = 0.f;
            #pragma unroll
            for (int b = 0; b < 8; ++b) s += kpart[((size_t)h*8 + b)*64 + t];
            mu_s[t] = s * (1.0f/LL);
        }
        __syncthreads();
        size_t rowb = (size_t)h*LL + (size_t)ki*BK;
        float x[DD]; float n2 = 0.f;
        if (t < 64) {
            const float* rp = k + (rowb + t) * DD;
            #pragma unroll
            for (int d = 0; d < DD; d += 4) {
                float4 v4 = *(const float4*)(rp + d);
                v4.x -= mu_s[d]; v4.y -= mu_s[d+1]; v4.z -= mu_s[d+2]; v4.w -= mu_s[d+3];
                x[d]=v4.x; x[d+1]=v4.y; x[d+2]=v4.z; x[d+3]=v4.w;
                n2 += v4.x*v4.x + v4.y*v4.y + v4.z*v4.z + v4.w*v4.w;
            }
            #pragma unroll
            for (int d = 0; d < DD; d += 4) {
                ushort4 o;
                o.x = f2bf(x[d]);   o.y = f2bf(x[d+1]);
                o.z = f2bf(x[d+2]); o.w = f2bf(x[d+3]);
                *(ushort4*)(kb + (rowb + t)*DD + d) = o;
            }
            #pragma unroll
            for (int d = 0; d < DD; ++d) xs[t][d] = x[d];
        } else {
            int tk = t - 64;
            const float* vp = v + (rowb + tk) * DD;
            #pragma unroll
            for (int d = 0; d < DD; d += 4) {
                float4 v4 = *(const float4*)(vp + d);
                vs[tk][d]   = f2bf(v4.x); vs[tk][d+1] = f2bf(v4.y);
                vs[tk][d+2] = f2bf(v4.z); vs[tk][d+3] = f2bf(v4.w);
            }
        }
        __syncthreads();
        if (t < 64) {
            size_t vbase = ((size_t)h*DD + t)*LL + (size_t)ki*64;
            #pragma unroll
            for (int r8 = 0; r8 < 64; r8 += 8) {
                s8v o;
                #pragma unroll
                for (int e = 0; e < 8; ++e) o[e] = (short)vs[r8+e][t];
                *(s8v*)(vTb + vbase + r8) = o;
            }
            float s = 0.f;
            for (int r = 0; r < BK; ++r) s += xs[r][t];
            mean[t] = s * (1.0f/BK);
        }
        __syncthreads();
        if (t < 64) {
            float dot = 0.f, m2 = 0.f;
            #pragma unroll
            for (int d = 0; d < DD; ++d) { dot += x[d]*mean[d]; m2 += mean[d]*mean[d]; }
            float cs = dot / ((sqrtf(n2) + 1e-6f) * (sqrtf(m2) + 1e-6f));
            red[t] = cs;
        }
        __syncthreads();
        for (int sft = 32; sft > 0; sft >>= 1) {
            if (t < sft) red[t] += red[t + sft];
            __syncthreads();
        }
        if (t == 0) compk[h*NK + ki] = (red[0] * (1.0f/BK)) > simth[h] ? 1 : 0;
        if (t < 64) km[((size_t)h*NK + ki)*DD + t] = mean[t];
    }

    // ---- last-block-per-head bmask (atomic counter; no grid sync) ----
    __shared__ int lastFlag;
    __threadfence();                      // release this block's global writes
    __syncthreads();
    if (t == 0) {
        int old = atomicAdd(&cnt[h], 1);
        lastFlag = (old == NQ + NK - 1) ? 1 : 0;
    }
    __syncthreads();
    if (lastFlag) {
        __threadfence();                  // acquire: see all 48 blocks' writes
        int grp = t >> 5, j = t & 31;     // 4 groups of 32 lanes
        float* ssh = (float*)smem + grp*64;
        float* pp  = ssh + 32;
        for (int qq = grp; qq < NQ; qq += 4) {
            const float* qv = qm + ((size_t)h*NQ + qq)*DD;
            const float* kv = km + ((size_t)h*NK + j)*DD;
            float s = 0.f;
            for (int d = 0; d < DD; ++d) s += qv[d]*kv[d];
            ssh[j] = s * SCALE;
            __syncthreads();
            {
                float m = ssh[0];
                for (int i = 1; i < NK; ++i) m = fmaxf(m, ssh[i]);
                float den = 0.f;
                for (int i = 0; i < NK; ++i) den += expf(ssh[i] - m);
                pp[j] = expf(ssh[j] - m) / den;
            }
            __syncthreads();
            {
                float pj = pp[j];
                float mass = 0.f;
                for (int i = 0; i < NK; ++i) {
                    float pi = pp[i];
                    if (pi > pj || (pi == pj && i < j)) mass += pi;
                }
                int sel = (mass < cdfth[h]) ? 1 : 0;
                int keep = (sel || !(compq[h*NQ+qq] && compk[h*NK+j])) ? 1 : 0;
                unsigned long long bal = __ballot(keep);
                unsigned msk32 = (grp & 1) ? (unsigned)(bal >> 32) : (unsigned)bal;
                if (j == 0) bmaskbits[h*NQ + qq] = msk32;
            }
            __syncthreads();
        }
    }
}

// ---------------- kernel 3: wave-autonomous masked flash attention (64q/wave) ----------------
// r15's proven kernel VERBATIM (attn 43 us): external bitmask, block =
// (h, qi, half) via XCD-aware 1D grid, 4 waves rank-splitting the selected
// k-blocks, 64q x 64k per iter, direct-from-L2 fragments, V after QK^T.
__global__ __launch_bounds__(256, 2) void attn_kernel(
        const ushort* __restrict__ qb, const ushort* __restrict__ kb,
        const ushort* __restrict__ vTb, const unsigned* __restrict__ bmaskbits,
        float* __restrict__ out) {
    // LDS: [0,36864) per-wave P tiles [64][72] ushort (main loop),
    //      UNION [0,67584) O-merge [4][64][66] f32 (epilogue),
    //      [67584,68608) m[4][64], [68608,69632) l[4][64]
    __shared__ __align__(16) char shmem[69632];
    ushort* pl = (ushort*)shmem + (threadIdx.x >> 6) * 64 * 72;
    float*  Ob = (float*)shmem;                     // stride 4224 floats per wave
    float*  mb = (float*)(shmem + 67584);
    float*  lb = (float*)(shmem + 68608);

    int bid  = blockIdx.x;
    int slot = bid >> 3;
    int h    = ((slot >> 5) << 3) | (bid & 7);
    int qi   = (slot & 31) >> 1;
    int half = slot & 1;
    int tid  = threadIdx.x;
    int w    = tid >> 6;
    int l    = tid & 63;
    int lo = l & 15, hi = l >> 4;
    int r0 = qi*BQ + half*64;                // base of this block's 64 q-rows

    unsigned msk = bmaskbits[h*NQ + qi];

    const ushort* qh = qb  + (size_t)h*LL*DD;
    const ushort* kh = kb  + (size_t)h*LL*DD;
    const ushort* vh = vTb + (size_t)h*DD*LL;

    // Q B-frags for all 4 q-tiles
    s8v qf[4][2];
    #pragma unroll
    for (int qt = 0; qt < 4; ++qt)
        #pragma unroll
        for (int kk = 0; kk < 2; ++kk)
            qf[qt][kk] = *(const s8v*)(qh + (size_t)(r0 + qt*16 + lo)*DD + kk*32 + hi*8);

    f4v O[4][4];
    float m[4], lsum[4];
    #pragma unroll
    for (int qt = 0; qt < 4; ++qt) {
        m[qt] = -1e30f; lsum[qt] = 0.f;
        #pragma unroll
        for (int dt = 0; dt < 4; ++dt) O[qt][dt] = (f4v){0.f,0.f,0.f,0.f};
    }

    unsigned mm = msk; int rank = 0;
    while (mm) {
        int j = __ffs(mm) - 1; mm &= mm - 1;
        if (((rank++) & 3) != w) continue;     // rank-split across waves

        const ushort* kbj = kh + (size_t)j*BK*DD;
        const ushort* vbj = vh + (size_t)j*BK;

        // K A-frags direct from L2
        s8v kf[4][2];
        #pragma unroll
        for (int kt = 0; kt < 4; ++kt)
            #pragma unroll
            for (int kk = 0; kk < 2; ++kk)
                kf[kt][kk] = *(const s8v*)(kbj + (size_t)(kt*16 + lo)*DD + kk*32 + hi*8);

        // S^T = K . Q^T : lane holds S[k=kt*16+hi*4+r][q=qt*16+lo]
        f4v S[4][4];
        #pragma unroll
        for (int kt = 0; kt < 4; ++kt)
            #pragma unroll
            for (int qt = 0; qt < 4; ++qt)
                S[kt][qt] = (f4v){0.f,0.f,0.f,0.f};
        __builtin_amdgcn_s_setprio(1);
        #pragma unroll
        for (int kk = 0; kk < 2; ++kk)
            #pragma unroll
            for (int kt = 0; kt < 4; ++kt)
                #pragma unroll
                for (int qt = 0; qt < 4; ++qt)
                    S[kt][qt] = __builtin_amdgcn_mfma_f32_16x16x32_bf16(kf[kt][kk], qf[qt][kk], S[kt][qt], 0, 0, 0);
        __builtin_amdgcn_s_setprio(0);

        // V B-frags after QK^T: latency hides under softmax + P pack
        s8v vf[2][4];
        #pragma unroll
        for (int kk = 0; kk < 2; ++kk)
            #pragma unroll
            for (int dt = 0; dt < 4; ++dt)
                vf[kk][dt] = *(const s8v*)(vbj + (size_t)(dt*16 + lo)*LL + kk*32 + hi*8);

        // per-q (=qt*16+lo) max over this wave's 64 k
        float pm[4];
        #pragma unroll
        for (int qt = 0; qt < 4; ++qt) {
            float a0 = fmaxf(fmaxf(S[0][qt][0],S[0][qt][1]), fmaxf(S[0][qt][2],S[0][qt][3]));
            float a1 = fmaxf(fmaxf(S[1][qt][0],S[1][qt][1]), fmaxf(S[1][qt][2],S[1][qt][3]));
            float a2 = fmaxf(fmaxf(S[2][qt][0],S[2][qt][1]), fmaxf(S[2][qt][2],S[2][qt][3]));
            float a3 = fmaxf(fmaxf(S[3][qt][0],S[3][qt][1]), fmaxf(S[3][qt][2],S[3][qt][3]));
            float p = fmaxf(fmaxf(a0,a1), fmaxf(a2,a3));
            p = fmaxf(p, __shfl_xor(p, 16));
            p = fmaxf(p, __shfl_xor(p, 32));
            pm[qt] = p;
        }
        bool grow = (pm[0] > m[0]+8.0f) | (pm[1] > m[1]+8.0f) |
                    (pm[2] > m[2]+8.0f) | (pm[3] > m[3]+8.0f);
        if (__any(grow)) {                      // defer-max (T13)
            float alpha[4];
            #pragma unroll
            for (int qt = 0; qt < 4; ++qt) {
                float mn = fmaxf(m[qt], pm[qt]);
                alpha[qt] = __builtin_amdgcn_exp2f(m[qt] - mn);
                lsum[qt] *= alpha[qt];
                m[qt] = mn;
            }
            #pragma unroll
            for (int qt = 0; qt < 4; ++qt)
                #pragma unroll
                for (int r = 0; r < 4; ++r) {
                    float a = __shfl(alpha[qt], hi*4 + r);   // alpha of q-row qt*16+hi*4+r
                    #pragma unroll
                    for (int dt = 0; dt < 4; ++dt) O[qt][dt][r] *= a;
                }
        }
        // P = exp2(S - m), pack to per-wave plds [q][k] (stride 72)
        #pragma unroll
        for (int qt = 0; qt < 4; ++qt) {
            float ps = 0.f;
            #pragma unroll
            for (int kt = 0; kt < 4; ++kt) {
                float p0 = __builtin_amdgcn_exp2f(S[kt][qt][0] - m[qt]);
                float p1 = __builtin_amdgcn_exp2f(S[kt][qt][1] - m[qt]);
                float p2 = __builtin_amdgcn_exp2f(S[kt][qt][2] - m[qt]);
                float p3 = __builtin_amdgcn_exp2f(S[kt][qt][3] - m[qt]);
                ps += (p0 + p1) + (p2 + p3);
                unsigned c01, c23;
                asm("v_cvt_pk_bf16_f32 %0, %1, %2" : "=v"(c01) : "v"(p0), "v"(p1));
                asm("v_cvt_pk_bf16_f32 %0, %1, %2" : "=v"(c23) : "v"(p2), "v"(p3));
                *(uint2*)&pl[(qt*16 + lo)*72 + kt*16 + hi*4] = make_uint2(c01, c23);
            }
            lsum[qt] += ps;
        }
        // PV: O[q][d] += P . V  (P as A-frag from plds; V from regs)
        __builtin_amdgcn_s_setprio(1);
        #pragma unroll
        for (int qt = 0; qt < 4; ++qt)
            #pragma unroll
            for (int kk = 0; kk < 2; ++kk) {
                s8v pa = *(const s8v*)&pl[(qt*16 + lo)*72 + kk*32 + hi*8];
                #pragma unroll
                for (int dt = 0; dt < 4; ++dt)
                    O[qt][dt] = __builtin_amdgcn_mfma_f32_16x16x32_bf16(pa, vf[kk][dt], O[qt][dt], 0, 0, 0);
            }
        __builtin_amdgcn_s_setprio(0);
    }

    // finish per-wave row-sums (reduce over hi groups)
    #pragma unroll
    for (int qt = 0; qt < 4; ++qt) {
        lsum[qt] += __shfl_xor(lsum[qt], 16);
        lsum[qt] += __shfl_xor(lsum[qt], 32);
    }

    __syncthreads();    // all waves done with plds (Ob overlaps it)

    if (hi == 0) {
        #pragma unroll
        for (int qt = 0; qt < 4; ++qt) {
            mb[w*64 + qt*16 + lo] = m[qt];
            lb[w*64 + qt*16 + lo] = lsum[qt];
        }
    }
    #pragma unroll
    for (int qt = 0; qt < 4; ++qt)
        #pragma unroll
        for (int dt = 0; dt < 4; ++dt)
            #pragma unroll
            for (int r = 0; r < 4; ++r)
                Ob[w*4224 + (qt*16 + hi*4 + r)*66 + dt*16 + lo] = O[qt][dt][r];
    __syncthreads();

    // merge: lane q = l handles all 64 q-rows' d-slice [w*16, w*16+16)
    {
        int q = l;
        float mw0 = mb[q], mw1 = mb[64+q], mw2 = mb[128+q], mw3 = mb[192+q];
        float ms = fmaxf(fmaxf(mw0,mw1), fmaxf(mw2,mw3));
        float c0 = __builtin_amdgcn_exp2f(mw0 - ms);
        float c1 = __builtin_amdgcn_exp2f(mw1 - ms);
        float c2 = __builtin_amdgcn_exp2f(mw2 - ms);
        float c3 = __builtin_amdgcn_exp2f(mw3 - ms);
        float ls = lb[q]*c0 + lb[64+q]*c1 + lb[128+q]*c2 + lb[192+q]*c3;
        float inv = 1.0f / ls;
        float* orow = out + ((size_t)h*LL + r0 + q)*DD + w*16;
        #pragma unroll
        for (int i4 = 0; i4 < 4; ++i4) {
            float4 o;
            #pragma unroll
            for (int e = 0; e < 4; ++e) {
                int d = w*16 + i4*4 + e;
                float acc = Ob[q*66 + d]*c0 + Ob[4224 + q*66 + d]*c1
                          + Ob[8448 + q*66 + d]*c2 + Ob[12672 + q*66 + d]*c3;
                ((float*)&o)[e] = acc * inv;
            }
            *(float4*)(orow + i4*4) = o;
        }
    }
}

extern "C" void kernel_launch(void* const* d_in, const int* in_sizes, int n_in,
                              void* d_out, int out_size, void* d_ws, size_t ws_size,
                              hipStream_t stream) {
    const float* q     = (const float*)d_in[0];
    const float* k     = (const float*)d_in[1];
    const float* v     = (const float*)d_in[2];
    const float* simth = (const float*)d_in[3];
    const float* cdfth = (const float*)d_in[4];
    float* out = (float*)d_out;

    float* ws    = (float*)d_ws;
    float* kpart = ws;                       // 16*8*64
    float* qm    = kpart + HH*8*64;          // 16*16*64
    float* km    = qm + HH*NQ*DD;            // 16*32*64
    int*   compq = (int*)(km + HH*NK*DD);    // 256
    int*   compk = compq + HH*NQ;            // 512
    unsigned* bmb = (unsigned*)(compk + HH*NK);  // 256
    int*   cnt   = (int*)(bmb + HH*NQ);      // 16
    size_t off = (size_t)((char*)(cnt + HH) - (char*)d_ws);
    off = (off + 15) & ~(size_t)15;
    ushort* qbuf = (ushort*)((char*)d_ws + off);
    ushort* kbuf = qbuf + (size_t)HH*LL*DD;
    ushort* vTb  = kbuf + (size_t)HH*LL*DD;

    kmean1_kernel<<<dim3(8, HH), 256, 0, stream>>>(k, kpart, cnt);
    stats_kernel<<<dim3(NQ + NK, HH), 128, 0, stream>>>(q, k, v, kpart, simth,
                                                        qm, km, compq, compk,
                                                        qbuf, kbuf, vTb,
                                                        cdfth, bmb, cnt);
    attn_kernel<<<dim3(NQ*2*HH), 256, 0, stream>>>(qbuf, kbuf, vTb, bmb, out);
}

// Round 22
// 71.321 us; speedup vs baseline: 3.7054x; 2.1099x over previous
//
#include <hip/hip_runtime.h>

#define HH 16
#define LL 2048
#define DD 64
#define BQ 128
#define BK 64
#define NQ (LL/BQ)   /* 16 */
#define NK (LL/BK)   /* 32 */
#define SCALE 0.125f
#define QSCALE (0.125f * 1.44269504f)   /* fold log2(e): softmax via exp2 */

typedef __attribute__((ext_vector_type(8))) short s8v;   // 8 bf16 (4 VGPR)
typedef __attribute__((ext_vector_type(4))) float f4v;   // 4 fp32 acc

static __device__ __forceinline__ ushort f2bf(float x) {
    unsigned u = __float_as_uint(x);
    u += 0x7fff + ((u >> 16) & 1);       // round-to-nearest-even
    return (ushort)(u >> 16);
}

// ---------------- kernel 1: per-head k partial sums ----------------
__global__ void kmean1_kernel(const float* __restrict__ k, float* __restrict__ kpart) {
    int b = blockIdx.x;             // 0..7 token slab of 256
    int h = blockIdx.y;
    int t = threadIdx.x;            // 256
    int d = t & 63, c = t >> 6;
    const float* kh = k + ((size_t)h*LL + (size_t)b*256) * DD;
    float s = 0.f;
    for (int l = c*64; l < c*64 + 64; ++l) s += kh[(size_t)l * DD + d];
    __shared__ float red[4][64];
    red[c][d] = s;
    __syncthreads();
    if (t < 64) kpart[((size_t)h*8 + b)*64 + t] = red[0][t]+red[1][t]+red[2][t]+red[3][t];
}

// ---------------- kernel 2: fused stats + bf16 converts ----------------
__global__ __launch_bounds__(128) void stats_kernel(
        const float* __restrict__ q, const float* __restrict__ k, const float* __restrict__ v,
        const float* __restrict__ kpart, const float* __restrict__ simth,
        float* __restrict__ qm, float* __restrict__ km,
        int* __restrict__ compq, int* __restrict__ compk,
        ushort* __restrict__ qb, ushort* __restrict__ kb, ushort* __restrict__ vTb) {
    __shared__ __align__(16) char smem[34304];
    int h = blockIdx.y, t = threadIdx.x;

    if ((int)blockIdx.x < NQ) {
        // ---------- q path ----------
        int qi = blockIdx.x;
        float (*xs)[DD+1] = (float(*)[DD+1])smem;         // 128*65*4 = 33280
        float* mean = (float*)(smem + 33280);             // 256
        float* red  = (float*)(smem + 33536);             // 512
        size_t row = (size_t)h*LL + (size_t)qi*BQ + t;
        const float* rp = q + row * DD;
        float x[DD]; float n2 = 0.f;
        #pragma unroll
        for (int d = 0; d < DD; d += 4) {
            float4 v4 = *(const float4*)(rp + d);
            x[d]=v4.x; x[d+1]=v4.y; x[d+2]=v4.z; x[d+3]=v4.w;
            n2 += v4.x*v4.x + v4.y*v4.y + v4.z*v4.z + v4.w*v4.w;
        }
        #pragma unroll
        for (int d = 0; d < DD; d += 4) {
            ushort4 o;
            o.x = f2bf(x[d]*QSCALE);   o.y = f2bf(x[d+1]*QSCALE);
            o.z = f2bf(x[d+2]*QSCALE); o.w = f2bf(x[d+3]*QSCALE);
            *(ushort4*)(qb + row*DD + d) = o;
        }
        #pragma unroll
        for (int d = 0; d < DD; ++d) xs[t][d] = x[d];
        __syncthreads();
        {   // parallel partial column sums: thread t = (half, d)
            int d = t & 63, hf = t >> 6;
            float s = 0.f;
            for (int r = hf*64; r < hf*64 + 64; ++r) s += xs[r][d];
            red[t] = s;
        }
        __syncthreads();
        if (t < DD) mean[t] = (red[t] + red[64 + t]) * (1.0f/BQ);
        __syncthreads();
        float dot = 0.f, m2 = 0.f;
        #pragma unroll
        for (int d = 0; d < DD; ++d) { dot += x[d]*mean[d]; m2 += mean[d]*mean[d]; }
        float cs = dot / ((sqrtf(n2) + 1e-6f) * (sqrtf(m2) + 1e-6f));
        __syncthreads();
        red[t] = cs; __syncthreads();
        for (int sft = BQ/2; sft > 0; sft >>= 1) {
            if (t < sft) red[t] += red[t + sft];
            __syncthreads();
        }
        if (t == 0) compq[h*NQ + qi] = (red[0] * (1.0f/BQ)) > simth[h] ? 1 : 0;
        if (t < DD) qm[((size_t)h*NQ + qi)*DD + t] = mean[t];
    } else {
        // ---------- k/v path ----------
        int ki = blockIdx.x - NQ;
        float* mu_s = (float*)smem;                               // 256
        float (*xs)[DD+1] = (float(*)[DD+1])(smem + 256);         // 64*65*4 = 16640
        ushort (*vs)[66]  = (ushort(*)[66])(smem + 256 + 16640);  // 8448
        float* mean = (float*)(smem + 256 + 16640 + 8448);        // 256
        float* red  = (float*)(smem + 256 + 16640 + 8448 + 256);  // 256
        if (t < 64) {
            float s = 0.f;
            #pragma unroll
            for (int b = 0; b < 8; ++b) s += kpart[((size_t)h*8 + b)*64 + t];
            mu_s[t] = s * (1.0f/LL);
        }
        __syncthreads();
        size_t rowb = (size_t)h*LL + (size_t)ki*BK;
        float x[DD]; float n2 = 0.f;
        if (t < 64) {
            const float* rp = k + (rowb + t) * DD;
            #pragma unroll
            for (int d = 0; d < DD; d += 4) {
                float4 v4 = *(const float4*)(rp + d);
                v4.x -= mu_s[d]; v4.y -= mu_s[d+1]; v4.z -= mu_s[d+2]; v4.w -= mu_s[d+3];
                x[d]=v4.x; x[d+1]=v4.y; x[d+2]=v4.z; x[d+3]=v4.w;
                n2 += v4.x*v4.x + v4.y*v4.y + v4.z*v4.z + v4.w*v4.w;
            }
            #pragma unroll
            for (int d = 0; d < DD; d += 4) {
                ushort4 o;
                o.x = f2bf(x[d]);   o.y = f2bf(x[d+1]);
                o.z = f2bf(x[d+2]); o.w = f2bf(x[d+3]);
                *(ushort4*)(kb + (rowb + t)*DD + d) = o;
            }
            #pragma unroll
            for (int d = 0; d < DD; ++d) xs[t][d] = x[d];
        } else {
            int tk = t - 64;
            const float* vp = v + (rowb + tk) * DD;
            #pragma unroll
            for (int d = 0; d < DD; d += 4) {
                float4 v4 = *(const float4*)(vp + d);
                vs[tk][d]   = f2bf(v4.x); vs[tk][d+1] = f2bf(v4.y);
                vs[tk][d+2] = f2bf(v4.z); vs[tk][d+3] = f2bf(v4.w);
            }
        }
        __syncthreads();
        if (t < 64) {
            size_t vbase = ((size_t)h*DD + t)*LL + (size_t)ki*64;
            #pragma unroll
            for (int r8 = 0; r8 < 64; r8 += 8) {
                s8v o;
                #pragma unroll
                for (int e = 0; e < 8; ++e) o[e] = (short)vs[r8+e][t];
                *(s8v*)(vTb + vbase + r8) = o;
            }
            float s = 0.f;
            for (int r = 0; r < BK; ++r) s += xs[r][t];
            mean[t] = s * (1.0f/BK);
        }
        __syncthreads();
        if (t < 64) {
            float dot = 0.f, m2 = 0.f;
            #pragma unroll
            for (int d = 0; d < DD; ++d) { dot += x[d]*mean[d]; m2 += mean[d]*mean[d]; }
            float cs = dot / ((sqrtf(n2) + 1e-6f) * (sqrtf(m2) + 1e-6f));
            red[t] = cs;
        }
        __syncthreads();
        for (int sft = 32; sft > 0; sft >>= 1) {
            if (t < sft) red[t] += red[t + sft];
            __syncthreads();
        }
        if (t == 0) compk[h*NK + ki] = (red[0] * (1.0f/BK)) > simth[h] ? 1 : 0;
        if (t < 64) km[((size_t)h*NK + ki)*DD + t] = mean[t];
    }
}

// ---------------- kernel 3: wave-autonomous masked flash attention (64q/wave) ----------------
// Best measured configuration (r19, 71.6 us total): bmask computed by WAVE 0
// ONLY and broadcast via LDS scalar + one uniform barrier; 64q/wave loop with
// direct-from-L2 MFMA fragments; XCD-aware 1D grid; 3 launches total.
__global__ __launch_bounds__(256, 2) void attn_kernel(
        const ushort* __restrict__ qb, const ushort* __restrict__ kb,
        const ushort* __restrict__ vTb,
        const float* __restrict__ qm, const float* __restrict__ km,
        const int* __restrict__ compq, const int* __restrict__ compk,
        const float* __restrict__ cdfth, float* __restrict__ out) {
    // LDS: [0,36864) per-wave P tiles [64][72] ushort (wave0's first 256B
    //      double as bmask scratch pre-loop),
    //      UNION [0,67584) O-merge [4][64][66] f32 (epilogue),
    //      [67584,68608) m[4][64], [68608,69632) l[4][64], [69632] mskS
    __shared__ __align__(16) char shmem[69640];
    ushort* pl = (ushort*)shmem + (threadIdx.x >> 6) * 64 * 72;
    float*  Ob = (float*)shmem;                     // stride 4224 floats per wave
    float*  mb = (float*)(shmem + 67584);
    float*  lb = (float*)(shmem + 68608);
    unsigned* mskS = (unsigned*)(shmem + 69632);

    int bid  = blockIdx.x;
    int slot = bid >> 3;
    int h    = ((slot >> 5) << 3) | (bid & 7);
    int qi   = (slot & 31) >> 1;
    int half = slot & 1;
    int tid  = threadIdx.x;
    int w    = tid >> 6;
    int l    = tid & 63;
    int lo = l & 15, hi = l >> 4;
    int r0 = qi*BQ + half*64;                // base of this block's 64 q-rows

    const ushort* qh = qb  + (size_t)h*LL*DD;
    const ushort* kh = kb  + (size_t)h*LL*DD;
    const ushort* vh = vTb + (size_t)h*DD*LL;

    // Q B-frags issued early (all waves); latency hides under wave-0 bmask
    s8v qf[4][2];
    #pragma unroll
    for (int qt = 0; qt < 4; ++qt)
        #pragma unroll
        for (int kk = 0; kk < 2; ++kk)
            qf[qt][kk] = *(const s8v*)(qh + (size_t)(r0 + qt*16 + lo)*DD + kk*32 + hi*8);

    // ---- bmask: wave 0 only, LDS-array ascending sums (byte-identical math) ----
    if (tid < 64) {
        float* ebw = (float*)pl;          // wave 0's private scratch
        float* pbw = ebw + 32;
        int j = l & 31;
        const float* qv = qm + ((size_t)h*NQ + qi)*DD;
        const float* kv = km + ((size_t)h*NK + j)*DD;
        float s = 0.f;
        #pragma unroll
        for (int d = 0; d < DD; d += 4) {      // float4 loads, same add order
            float4 a = *(const float4*)(qv + d);
            float4 b = *(const float4*)(kv + d);
            s += a.x*b.x; s += a.y*b.y; s += a.z*b.z; s += a.w*b.w;
        }
        s *= SCALE;
        float mx = s;
        #pragma unroll
        for (int xm = 1; xm <= 16; xm <<= 1) mx = fmaxf(mx, __shfl_xor(mx, xm, 32));
        float e = expf(s - mx);
        ebw[j] = e;                            // lanes j and j+32 write same value
        float den = 0.f;
        #pragma unroll
        for (int i = 0; i < 32; ++i) den += ebw[i];   // ascending, bit-exact
        float p = e / den;
        pbw[j] = p;
        float mass = 0.f;
        #pragma unroll
        for (int i = 0; i < 32; ++i) {
            float pi = pbw[i];
            if (pi > p || (pi == p && i < j)) mass += pi;
        }
        int keep = (mass < cdfth[h]) || !(compq[h*NQ+qi] && compk[h*NK+j]);
        unsigned long long bal = __ballot(keep != 0);
        if (l == 0) *mskS = (unsigned)bal;
    }
    __syncthreads();
    unsigned msk = *mskS;

    f4v O[4][4];
    float m[4], lsum[4];
    #pragma unroll
    for (int qt = 0; qt < 4; ++qt) {
        m[qt] = -1e30f; lsum[qt] = 0.f;
        #pragma unroll
        for (int dt = 0; dt < 4; ++dt) O[qt][dt] = (f4v){0.f,0.f,0.f,0.f};
    }

    unsigned mm = msk; int rank = 0;
    while (mm) {
        int j = __ffs(mm) - 1; mm &= mm - 1;
        if (((rank++) & 3) != w) continue;     // rank-split across waves

        const ushort* kbj = kh + (size_t)j*BK*DD;
        const ushort* vbj = vh + (size_t)j*BK;

        // K A-frags direct from L2
        s8v kf[4][2];
        #pragma unroll
        for (int kt = 0; kt < 4; ++kt)
            #pragma unroll
            for (int kk = 0; kk < 2; ++kk)
                kf[kt][kk] = *(const s8v*)(kbj + (size_t)(kt*16 + lo)*DD + kk*32 + hi*8);

        // S^T = K . Q^T : lane holds S[k=kt*16+hi*4+r][q=qt*16+lo]
        f4v S[4][4];
        #pragma unroll
        for (int kt = 0; kt < 4; ++kt)
            #pragma unroll
            for (int qt = 0; qt < 4; ++qt)
                S[kt][qt] = (f4v){0.f,0.f,0.f,0.f};
        __builtin_amdgcn_s_setprio(1);
        #pragma unroll
        for (int kk = 0; kk < 2; ++kk)
            #pragma unroll
            for (int kt = 0; kt < 4; ++kt)
                #pragma unroll
                for (int qt = 0; qt < 4; ++qt)
                    S[kt][qt] = __builtin_amdgcn_mfma_f32_16x16x32_bf16(kf[kt][kk], qf[qt][kk], S[kt][qt], 0, 0, 0);
        __builtin_amdgcn_s_setprio(0);

        // V B-frags after QK^T: latency hides under softmax + P pack
        s8v vf[2][4];
        #pragma unroll
        for (int kk = 0; kk < 2; ++kk)
            #pragma unroll
            for (int dt = 0; dt < 4; ++dt)
                vf[kk][dt] = *(const s8v*)(vbj + (size_t)(dt*16 + lo)*LL + kk*32 + hi*8);

        // per-q (=qt*16+lo) max over this wave's 64 k
        float pm[4];
        #pragma unroll
        for (int qt = 0; qt < 4; ++qt) {
            float a0 = fmaxf(fmaxf(S[0][qt][0],S[0][qt][1]), fmaxf(S[0][qt][2],S[0][qt][3]));
            float a1 = fmaxf(fmaxf(S[1][qt][0],S[1][qt][1]), fmaxf(S[1][qt][2],S[1][qt][3]));
            float a2 = fmaxf(fmaxf(S[2][qt][0],S[2][qt][1]), fmaxf(S[2][qt][2],S[2][qt][3]));
            float a3 = fmaxf(fmaxf(S[3][qt][0],S[3][qt][1]), fmaxf(S[3][qt][2],S[3][qt][3]));
            float p = fmaxf(fmaxf(a0,a1), fmaxf(a2,a3));
            p = fmaxf(p, __shfl_xor(p, 16));
            p = fmaxf(p, __shfl_xor(p, 32));
            pm[qt] = p;
        }
        bool grow = (pm[0] > m[0]+8.0f) | (pm[1] > m[1]+8.0f) |
                    (pm[2] > m[2]+8.0f) | (pm[3] > m[3]+8.0f);
        if (__any(grow)) {                      // defer-max (T13)
            float alpha[4];
            #pragma unroll
            for (int qt = 0; qt < 4; ++qt) {
                float mn = fmaxf(m[qt], pm[qt]);
                alpha[qt] = __builtin_amdgcn_exp2f(m[qt] - mn);
                lsum[qt] *= alpha[qt];
                m[qt] = mn;
            }
            #pragma unroll
            for (int qt = 0; qt < 4; ++qt)
                #pragma unroll
                for (int r = 0; r < 4; ++r) {
                    float a = __shfl(alpha[qt], hi*4 + r);   // alpha of q-row qt*16+hi*4+r
                    #pragma unroll
                    for (int dt = 0; dt < 4; ++dt) O[qt][dt][r] *= a;
                }
        }
        // P = exp2(S - m), pack to per-wave plds [q][k] (stride 72)
        #pragma unroll
        for (int qt = 0; qt < 4; ++qt) {
            float ps = 0.f;
            #pragma unroll
            for (int kt = 0; kt < 4; ++kt) {
                float p0 = __builtin_amdgcn_exp2f(S[kt][qt][0] - m[qt]);
                float p1 = __builtin_amdgcn_exp2f(S[kt][qt][1] - m[qt]);
                float p2 = __builtin_amdgcn_exp2f(S[kt][qt][2] - m[qt]);
                float p3 = __builtin_amdgcn_exp2f(S[kt][qt][3] - m[qt]);
                ps += (p0 + p1) + (p2 + p3);
                unsigned c01, c23;
                asm("v_cvt_pk_bf16_f32 %0, %1, %2" : "=v"(c01) : "v"(p0), "v"(p1));
                asm("v_cvt_pk_bf16_f32 %0, %1, %2" : "=v"(c23) : "v"(p2), "v"(p3));
                *(uint2*)&pl[(qt*16 + lo)*72 + kt*16 + hi*4] = make_uint2(c01, c23);
            }
            lsum[qt] += ps;
        }
        // PV: O[q][d] += P . V  (P as A-frag from plds; V from regs)
        __builtin_amdgcn_s_setprio(1);
        #pragma unroll
        for (int qt = 0; qt < 4; ++qt)
            #pragma unroll
            for (int kk = 0; kk < 2; ++kk) {
                s8v pa = *(const s8v*)&pl[(qt*16 + lo)*72 + kk*32 + hi*8];
                #pragma unroll
                for (int dt = 0; dt < 4; ++dt)
                    O[qt][dt] = __builtin_amdgcn_mfma_f32_16x16x32_bf16(pa, vf[kk][dt], O[qt][dt], 0, 0, 0);
            }
        __builtin_amdgcn_s_setprio(0);
    }

    // finish per-wave row-sums (reduce over hi groups)
    #pragma unroll
    for (int qt = 0; qt < 4; ++qt) {
        lsum[qt] += __shfl_xor(lsum[qt], 16);
        lsum[qt] += __shfl_xor(lsum[qt], 32);
    }

    __syncthreads();    // all waves done with plds (Ob overlaps it)

    if (hi == 0) {
        #pragma unroll
        for (int qt = 0; qt < 4; ++qt) {
            mb[w*64 + qt*16 + lo] = m[qt];
            lb[w*64 + qt*16 + lo] = lsum[qt];
        }
    }
    #pragma unroll
    for (int qt = 0; qt < 4; ++qt)
        #pragma unroll
        for (int dt = 0; dt < 4; ++dt)
            #pragma unroll
            for (int r = 0; r < 4; ++r)
                Ob[w*4224 + (qt*16 + hi*4 + r)*66 + dt*16 + lo] = O[qt][dt][r];
    __syncthreads();

    // merge: lane q = l handles all 64 q-rows' d-slice [w*16, w*16+16)
    {
        int q = l;
        float mw0 = mb[q], mw1 = mb[64+q], mw2 = mb[128+q], mw3 = mb[192+q];
        float ms = fmaxf(fmaxf(mw0,mw1), fmaxf(mw2,mw3));
        float c0 = __builtin_amdgcn_exp2f(mw0 - ms);
        float c1 = __builtin_amdgcn_exp2f(mw1 - ms);
        float c2 = __builtin_amdgcn_exp2f(mw2 - ms);
        float c3 = __builtin_amdgcn_exp2f(mw3 - ms);
        float ls = lb[q]*c0 + lb[64+q]*c1 + lb[128+q]*c2 + lb[192+q]*c3;
        float inv = 1.0f / ls;
        float* orow = out + ((size_t)h*LL + r0 + q)*DD + w*16;
        #pragma unroll
        for (int i4 = 0; i4 < 4; ++i4) {
            float4 o;
            #pragma unroll
            for (int e = 0; e < 4; ++e) {
                int d = w*16 + i4*4 + e;
                float acc = Ob[q*66 + d]*c0 + Ob[4224 + q*66 + d]*c1
                          + Ob[8448 + q*66 + d]*c2 + Ob[12672 + q*66 + d]*c3;
                ((float*)&o)[e] = acc * inv;
            }
            *(float4*)(orow + i4*4) = o;
        }
    }
}

extern "C" void kernel_launch(void* const* d_in, const int* in_sizes, int n_in,
                              void* d_out, int out_size, void* d_ws, size_t ws_size,
                              hipStream_t stream) {
    const float* q     = (const float*)d_in[0];
    const float* k     = (const float*)d_in[1];
    const float* v     = (const float*)d_in[2];
    const float* simth = (const float*)d_in[3];
    const float* cdfth = (const float*)d_in[4];
    float* out = (float*)d_out;

    float* ws    = (float*)d_ws;
    float* kpart = ws;                       // 16*8*64
    float* qm    = kpart + HH*8*64;          // 16*16*64
    float* km    = qm + HH*NQ*DD;            // 16*32*64
    int*   compq = (int*)(km + HH*NK*DD);    // 256
    int*   compk = compq + HH*NQ;            // 512
    size_t off = (size_t)((char*)(compk + HH*NK) - (char*)d_ws);
    off = (off + 15) & ~(size_t)15;
    ushort* qbuf = (ushort*)((char*)d_ws + off);
    ushort* kbuf = qbuf + (size_t)HH*LL*DD;
    ushort* vTb  = kbuf + (size_t)HH*LL*DD;

    kmean1_kernel<<<dim3(8, HH), 256, 0, stream>>>(k, kpart);
    stats_kernel<<<dim3(NQ + NK, HH), 128, 0, stream>>>(q, k, v, kpart, simth,
                                                        qm, km, compq, compk,
                                                        qbuf, kbuf, vTb);
    attn_kernel<<<dim3(NQ*2*HH), 256, 0, stream>>>(qbuf, kbuf, vTb,
                                                   qm, km, compq, compk, cdfth, out);
}